// Round 19
// baseline (292.214 us; speedup 1.0000x reference)
//
#include <hip/hip_runtime.h>
#include <hip/hip_fp16.h>

// QueryAwareGNN: N=100000, E=600000, DIN=768, H=128, G=100.
// Output (flat f32): tool_logits[99000] | query_logits[1000] | tool_batch_index[99000]

#define HDIM 128

typedef short s16x8 __attribute__((ext_vector_type(8)));
typedef unsigned short u16;
typedef unsigned short u16x8 __attribute__((ext_vector_type(8)));
typedef float f32x4 __attribute__((ext_vector_type(4)));

// split f32 into hi/lo bf16 (truncation hi; lo captures next 8 mantissa bits)
__device__ inline void split2(float f, u16& hi, u16& lo) {
  unsigned u = __builtin_bit_cast(unsigned, f);
  hi = (u16)(u >> 16);
  float fh = __builtin_bit_cast(float, u & 0xFFFF0000u);
  float fl = f - fh;
  lo = (u16)(__builtin_bit_cast(unsigned, fl) >> 16);
}

// round-to-nearest-even f32 -> bf16
__device__ inline u16 bf16rne(float f) {
  unsigned u = __builtin_bit_cast(unsigned, f);
  u += 0x7FFFu + ((u >> 16) & 1u);
  return (u16)(u >> 16);
}

// convert 8 f32 (two f32x4) -> s16x8 of bf16 (RNE)
__device__ inline s16x8 cvt8(f32x4 a, f32x4 b) {
  s16x8 r;
  r[0] = (short)bf16rne(a[0]); r[1] = (short)bf16rne(a[1]);
  r[2] = (short)bf16rne(a[2]); r[3] = (short)bf16rne(a[3]);
  r[4] = (short)bf16rne(b[0]); r[5] = (short)bf16rne(b[1]);
  r[6] = (short)bf16rne(b[2]); r[7] = (short)bf16rne(b[3]);
  return r;
}

// ---------------- prep: zero degi | posmap+batch | weight pre-split ----------------
// One kernel, three independent index segments.
// Weight tiled layout (R12): th[(k/32)][n][k%32] (each k-block = exact 8KB LDS image)

__global__ __launch_bounds__(256) void k_prep(int* __restrict__ degi, int N,
                                              const int* __restrict__ tool_idx,
                                              const int* __restrict__ query_idx,
                                              const int* __restrict__ batch_vec,
                                              int* __restrict__ pos,
                                              float* __restrict__ out,
                                              int n_tool, int n_query,
                                              const float* __restrict__ Wa,
                                              const float* __restrict__ W1,
                                              const float* __restrict__ W2,
                                              u16* __restrict__ tha, u16* __restrict__ tla,
                                              u16* __restrict__ th1, u16* __restrict__ tl1,
                                              u16* __restrict__ th2, u16* __restrict__ tl2,
                                              int na, int n1) {
  int g = blockIdx.x * 256 + threadIdx.x;
  if (g < N) degi[g] = 0;
  int g1 = g - N;
  if (g1 >= 0 && g1 < n_tool) {
    int nd = tool_idx[g1];
    pos[nd] = g1;
    out[n_tool + n_query + g1] = (float)batch_vec[nd];
  } else if (g1 >= n_tool && g1 < n_tool + n_query) {
    int q = g1 - n_tool;
    pos[query_idx[q]] = n_tool + q;
  }
  int g2 = g - N - n_tool - n_query;
  if (g2 >= 0 && g2 < na + 2 * n1) {
    const float* W;
    u16 *th, *tl;
    int idx;
    if (g2 < na) { W = Wa; th = tha; tl = tla; idx = g2; }
    else if (g2 < na + n1) { W = W1; th = th1; tl = tl1; idx = g2 - na; }
    else { W = W2; th = th2; tl = tl2; idx = g2 - na - n1; }
    int n = idx & 127, k = idx >> 7;
    u16 h, l;
    split2(W[idx], h, l);
    int o = ((k >> 5) << 12) | (n << 5) | (k & 31);
    th[o] = h;
    tl[o] = l;
  }
}

// ---------------- CSR build ----------------

__global__ __launch_bounds__(256) void k_count(const int* __restrict__ dst,
                                               int* __restrict__ degi, int E) {
  int g = blockIdx.x * 256 + threadIdx.x;
  if (g < E) atomicAdd(&degi[dst[g]], 1);
}

// scan1: per-256-block exclusive scan; also dinv (fused)
__global__ __launch_bounds__(256) void k_scan1(const int* __restrict__ in,
                                               int* __restrict__ out,
                                               int* __restrict__ bsum,
                                               float* __restrict__ dinv, int n) {
  __shared__ int s[256];
  int t = threadIdx.x, g = blockIdx.x * 256 + t;
  int v = (g < n) ? in[g] : 0;
  if (g < n) dinv[g] = rsqrtf((float)(v + 1));  // +1 self-loop
  s[t] = v;
  for (int off = 1; off < 256; off <<= 1) {
    __syncthreads();
    int x = (t >= off) ? s[t - off] : 0;
    __syncthreads();
    s[t] += x;
  }
  if (g < n) out[g] = s[t] - v;
  if (t == 255) bsum[blockIdx.x] = s[255];
}

// scan23: every block re-scans bsum (nb<=512) in LDS and applies its offsets.
__global__ __launch_bounds__(512) void k_scan23(int* __restrict__ row_start,
                                                const int* __restrict__ bsum,
                                                int nb, int n, int total) {
  __shared__ int s[512];
  int t = threadIdx.x;
  int v = (t < nb) ? bsum[t] : 0;
  s[t] = v;
  for (int off = 1; off < 512; off <<= 1) {
    __syncthreads();
    int x = (t >= off) ? s[t - off] : 0;
    __syncthreads();
    s[t] += x;
  }
  __syncthreads();           // s[t] = inclusive prefix of bsum
  int g = blockIdx.x * 512 + t;
  int bi = g >> 8;           // which 256-block this element came from
  int off = (bi == 0) ? 0 : s[bi - 1];
  if (g < n) row_start[g] += off;
  if (g == 0) row_start[n] = total;
}

// fill: claims slots by decrementing degi (dead after scan1) -> no fillc buffer.
// csr packed as int2 {src, norm-bits}: one 8B random write per edge.
__global__ __launch_bounds__(256) void k_fill(const int* __restrict__ src,
                                              const int* __restrict__ dst,
                                              const int* __restrict__ row_start,
                                              int* __restrict__ degi,
                                              const float* __restrict__ dinv,
                                              int2* __restrict__ csr, int E) {
  int g = blockIdx.x * 256 + threadIdx.x;
  if (g < E) {
    int s = src[g], d = dst[g];
    int p = atomicSub(&degi[d], 1) - 1;   // deg-1 .. 0, unique per edge
    int o = row_start[d] + p;
    float nr = dinv[s] * dinv[d];
    csr[o] = make_int2(s, __float_as_int(nr));
  }
}

// ---------------- MFMA GEMM: C[M,128] = A[M,K] @ W[K,128] (+bias) ----------------
// 256x128 tile, 512 threads (8 waves 4x2), BK=32. Halves per-block B staging
// cost and B L2 re-reads vs the 128-tile; same MFMA order -> bit-identical.
// AHALF=false: A f32, staged raw into LDS (pad-36), cvt8 at fragment load.
// AHALF=true: A bf16, staged into u16 LDS (pad-40), read directly as fragments.
// B split hi+lo bf16, pre-tiled, pad-40 rows, reg-staged.
// OUTT: 1 = fp16 out (m buffer), 2 = bf16 out (h buffer).

template <int K, bool BIAS, bool AHALF, int OUTT>
__global__ __launch_bounds__(512) void k_gemm_bf(const void* __restrict__ Av,
                                                 const u16* __restrict__ Bth,
                                                 const u16* __restrict__ Btl,
                                                 const float* __restrict__ bias,
                                                 void* __restrict__ Cv, int M) {
  __shared__ __align__(16) char AfRaw[AHALF ? 256 * 40 * 2 : 256 * 36 * 4];
  __shared__ u16 Bh[128][40];    // B transposed: Bh[n][k], stride 40 (80B rows)
  __shared__ u16 Bl[128][40];

  const int t = threadIdx.x;
  const int m0 = blockIdx.x << 8;      // 256 rows per block
  const int lane = t & 63, w = t >> 6; // 8 waves
  const int wm = (w >> 1) << 6;        // 0,64,128,192
  const int wn = (w & 1) << 6;         // 0,64
  const int fr = lane & 15;            // row (A) / col (B) within fragment
  const int fk = (lane >> 4) << 3;     // k offset within fragment
  const int srow = t >> 1;             // staging: row 0..255
  const int scol = (t & 1) << 4;       // staging: col 0 or 16 (elements)

  f32x4 acc[4][4] = {};
  const bool valid = (m0 + srow) < M;

  // A-staging state (one of the two sets is used per instantiation)
  const float* arowF = nullptr;
  const u16* arowH = nullptr;
  f32x4 v0 = {}, v1 = {}, v2 = {}, v3 = {};
  u16x8 ha0 = {}, ha1 = {};
  if constexpr (AHALF) {
    arowH = (const u16*)Av + (size_t)(m0 + srow) * K + scol;
    if (valid) {
      ha0 = *(const u16x8*)(arowH + 0);
      ha1 = *(const u16x8*)(arowH + 8);
    }
  } else {
    arowF = (const float*)Av + (size_t)(m0 + srow) * K + scol;
    if (valid) {
      v0 = *(const f32x4*)(arowF + 0);
      v1 = *(const f32x4*)(arowF + 4);
      v2 = *(const f32x4*)(arowF + 8);
      v3 = *(const f32x4*)(arowF + 12);
    }
  }

  for (int kb = 0; kb < K; kb += 32) {
    // ---- A stage into LDS
    if constexpr (AHALF) {
      u16(*AfH)[40] = (u16(*)[40])AfRaw;
      *(u16x8*)&AfH[srow][scol] = ha0;
      *(u16x8*)&AfH[srow][scol + 8] = ha1;
    } else {
      float(*AfF)[36] = (float(*)[36])AfRaw;
      *(f32x4*)&AfF[srow][scol + 0] = v0;
      *(f32x4*)&AfF[srow][scol + 4] = v1;
      *(f32x4*)&AfF[srow][scol + 8] = v2;
      *(f32x4*)&AfF[srow][scol + 12] = v3;
    }

    // ---- B stage: 512 threads x 16B each from pre-tiled hi and lo images
    {
      const u16* bsrc = Bth + ((size_t)(kb >> 5) << 12) + (t << 3);
      u16x8 p0 = *(const u16x8*)bsrc;
      const u16* bsrc2 = Btl + ((size_t)(kb >> 5) << 12) + (t << 3);
      u16x8 q0 = *(const u16x8*)bsrc2;
      int bn = t >> 2, bseg = (t & 3) << 3;
      *(u16x8*)&Bh[bn][bseg] = p0;
      *(u16x8*)&Bl[bn][bseg] = q0;
    }
    __syncthreads();

    // ---- prefetch next A tile into regs (latency hides under MFMA)
    if (valid && kb + 32 < K) {
      if constexpr (AHALF) {
        ha0 = *(const u16x8*)(arowH + kb + 32);
        ha1 = *(const u16x8*)(arowH + kb + 40);
      } else {
        const float* ap = arowF + kb + 32;
        v0 = *(const f32x4*)(ap + 0);
        v1 = *(const f32x4*)(ap + 4);
        v2 = *(const f32x4*)(ap + 8);
        v3 = *(const f32x4*)(ap + 12);
      }
    }

    // ---- fragments + 32 MFMAs
    s16x8 ah[4], bh[4], bl[4];
#pragma unroll
    for (int i = 0; i < 4; ++i) {
      if constexpr (AHALF) {
        u16(*AfH)[40] = (u16(*)[40])AfRaw;
        ah[i] = *(const s16x8*)&AfH[wm + (i << 4) + fr][fk];
      } else {
        float(*AfF)[36] = (float(*)[36])AfRaw;
        const float* ar = &AfF[wm + (i << 4) + fr][fk];
        f32x4 a0 = *(const f32x4*)(ar + 0);
        f32x4 a1 = *(const f32x4*)(ar + 4);
        ah[i] = cvt8(a0, a1);
      }
      bh[i] = *(const s16x8*)&Bh[wn + (i << 4) + fr][fk];
      bl[i] = *(const s16x8*)&Bl[wn + (i << 4) + fr][fk];
    }
#pragma unroll
    for (int i = 0; i < 4; ++i)
#pragma unroll
      for (int j = 0; j < 4; ++j) {
        acc[i][j] = __builtin_amdgcn_mfma_f32_16x16x32_bf16(ah[i], bh[j], acc[i][j], 0, 0, 0);
        acc[i][j] = __builtin_amdgcn_mfma_f32_16x16x32_bf16(ah[i], bl[j], acc[i][j], 0, 0, 0);
      }
    __syncthreads();
  }

  // ---- epilogue: C/D layout col=lane&15, row=(lane>>4)*4+reg
  const int cr = (lane >> 4) << 2;
#pragma unroll
  for (int i = 0; i < 4; ++i) {
    int mbase = m0 + wm + (i << 4) + cr;
#pragma unroll
    for (int j = 0; j < 4; ++j) {
      int n = wn + (j << 4) + fr;
      float bv = BIAS ? bias[n] : 0.0f;
#pragma unroll
      for (int r = 0; r < 4; ++r) {
        if (mbase + r < M) {
          float val = acc[i][j][r] + bv;
          if constexpr (OUTT == 1) {
            ((__half*)Cv)[(size_t)(mbase + r) * HDIM + n] = __float2half_rn(val);
          } else {
            ((u16*)Cv)[(size_t)(mbase + r) * HDIM + n] = bf16rne(val);
          }
        }
      }
    }
  }
}

// ---------------- gather + bias + relu + residual ----------------
// One wave per node; m fp16 (256B/row gathers), h bf16 (packed 2/lane).
// Edge (src,norm) packed int2, loaded 64-at-a-time and broadcast via shfl.
// 4-way unrolled edge loop with quad accumulator pairs.
// FINAL=true: fuse output projection and skip the h write.

template <bool FINAL>
__global__ __launch_bounds__(256) void k_gather(const __half2* __restrict__ m2,
                                                unsigned* __restrict__ h,
                                                const int* __restrict__ row_start,
                                                const int2* __restrict__ csr,
                                                const float* __restrict__ dinv,
                                                const float* __restrict__ bias,
                                                const float* __restrict__ Wout,
                                                const float* __restrict__ bout,
                                                const int* __restrict__ pos,
                                                float* __restrict__ out, int N) {
  int wid = (blockIdx.x * 256 + threadIdx.x) >> 6;
  int lane = threadIdx.x & 63;
  if (wid >= N) return;
  float di = dinv[wid];
  float sl = di * di;
  float2 mv = __half22float2(m2[(size_t)wid * 64 + lane]);
  float ax = mv.x * sl, ay = mv.y * sl;   // accumulator pair 0 (+self-loop)
  float bx = 0.f, by = 0.f;               // pair 1
  float cx = 0.f, cy = 0.f;               // pair 2
  float dx = 0.f, dy = 0.f;               // pair 3
  int e0 = row_start[wid], e1 = row_start[wid + 1];
  for (int base = e0; base < e1; base += 64) {
    int cnt = e1 - base;
    if (cnt > 64) cnt = 64;
    int sL = 0;
    float nL = 0.f;
    if (base + lane < e1) {
      int2 cv = csr[base + lane];
      sL = cv.x;
      nL = __int_as_float(cv.y);
    }
    int j = 0;
    for (; j + 3 < cnt; j += 4) {
      int s0 = __shfl(sL, j);
      int s1 = __shfl(sL, j + 1);
      int s2 = __shfl(sL, j + 2);
      int s3 = __shfl(sL, j + 3);
      float n0 = __shfl(nL, j);
      float n1 = __shfl(nL, j + 1);
      float n2 = __shfl(nL, j + 2);
      float n3 = __shfl(nL, j + 3);
      float2 u0 = __half22float2(m2[(size_t)s0 * 64 + lane]);
      float2 u1 = __half22float2(m2[(size_t)s1 * 64 + lane]);
      float2 u2 = __half22float2(m2[(size_t)s2 * 64 + lane]);
      float2 u3 = __half22float2(m2[(size_t)s3 * 64 + lane]);
      ax = fmaf(u0.x, n0, ax); ay = fmaf(u0.y, n0, ay);
      bx = fmaf(u1.x, n1, bx); by = fmaf(u1.y, n1, by);
      cx = fmaf(u2.x, n2, cx); cy = fmaf(u2.y, n2, cy);
      dx = fmaf(u3.x, n3, dx); dy = fmaf(u3.y, n3, dy);
    }
    for (; j + 1 < cnt; j += 2) {
      int s0 = __shfl(sL, j);
      int s1 = __shfl(sL, j + 1);
      float n0 = __shfl(nL, j);
      float n1 = __shfl(nL, j + 1);
      float2 u0 = __half22float2(m2[(size_t)s0 * 64 + lane]);
      float2 u1 = __half22float2(m2[(size_t)s1 * 64 + lane]);
      ax = fmaf(u0.x, n0, ax); ay = fmaf(u0.y, n0, ay);
      bx = fmaf(u1.x, n1, bx); by = fmaf(u1.y, n1, by);
    }
    if (j < cnt) {
      int s0 = __shfl(sL, j);
      float n0 = __shfl(nL, j);
      float2 u0 = __half22float2(m2[(size_t)s0 * 64 + lane]);
      ax = fmaf(u0.x, n0, ax); ay = fmaf(u0.y, n0, ay);
    }
  }
  ax += bx; cx += dx; ax += cx;
  ay += by; cy += dy; ay += cy;
  float2 bb = ((const float2*)bias)[lane];
  unsigned hw = h[(size_t)wid * 64 + lane];            // 2 bf16 packed
  float hvx = __builtin_bit_cast(float, (hw & 0xFFFFu) << 16);
  float hvy = __builtin_bit_cast(float, hw & 0xFFFF0000u);
  float rx = fmaxf(ax + bb.x, 0.f) + hvx;
  float ry = fmaxf(ay + bb.y, 0.f) + hvy;
  if (FINAL) {
    float2 wv = ((const float2*)Wout)[lane];
    float s = rx * wv.x + ry * wv.y;
#pragma unroll
    for (int off = 32; off > 0; off >>= 1) s += __shfl_down(s, off);
    if (lane == 0) out[pos[wid]] = s + bout[0];
  } else {
    unsigned wout = (unsigned)bf16rne(rx) | ((unsigned)bf16rne(ry) << 16);
    h[(size_t)wid * 64 + lane] = wout;
  }
}

// ---------------- launcher ----------------

extern "C" void kernel_launch(void* const* d_in, const int* in_sizes, int n_in,
                              void* d_out, int out_size, void* d_ws, size_t ws_size,
                              hipStream_t stream) {
  const float* x        = (const float*)d_in[0];
  const int*   edge_src = (const int*)d_in[1];
  const int*   edge_dst = (const int*)d_in[2];
  const int*   batch_vec= (const int*)d_in[3];
  const int*   tool_idx = (const int*)d_in[4];
  const int*   query_idx= (const int*)d_in[5];
  const float* W_align  = (const float*)d_in[6];
  const float* b_align  = (const float*)d_in[7];
  const float* W1       = (const float*)d_in[8];
  const float* b1       = (const float*)d_in[9];
  const float* W2       = (const float*)d_in[10];
  const float* b2       = (const float*)d_in[11];
  const float* W_out    = (const float*)d_in[12];
  const float* b_out    = (const float*)d_in[13];

  const int N   = in_sizes[3];
  const int E   = in_sizes[1];
  const int DIN = in_sizes[0] / N;     // 768
  const int n_tool  = in_sizes[4];
  const int n_query = in_sizes[5];
  (void)n_in; (void)out_size; (void)ws_size;

  char* p = (char*)d_ws;
  auto alloc = [&](size_t bytes) {
    void* r = (void*)p;
    p += (bytes + 255) & ~(size_t)255;
    return r;
  };
  int*   degi      = (int*)alloc((size_t)N * 4);
  float* dinv      = (float*)alloc((size_t)N * 4);
  int*   row_start = (int*)alloc((size_t)(N + 1) * 4);
  int*   pos       = (int*)alloc((size_t)N * 4);
  int2*  csr       = (int2*)alloc((size_t)E * 8);
  u16*   h         = (u16*)alloc((size_t)N * HDIM * 2);   // bf16 activations
  __half* m        = (__half*)alloc((size_t)N * HDIM * 2);
  int*   bsum      = (int*)alloc((size_t)1024 * 4);
  u16*   WthA      = (u16*)alloc((size_t)DIN * HDIM * 2);
  u16*   WtlA      = (u16*)alloc((size_t)DIN * HDIM * 2);
  u16*   Wth1      = (u16*)alloc((size_t)HDIM * HDIM * 2);
  u16*   Wtl1      = (u16*)alloc((size_t)HDIM * HDIM * 2);
  u16*   Wth2      = (u16*)alloc((size_t)HDIM * HDIM * 2);
  u16*   Wtl2      = (u16*)alloc((size_t)HDIM * HDIM * 2);

  const int nblkE = (E + 255) / 256;
  const int nblkN = (N + 255) / 256;   // 391 (<=512 required for scan23)
  const int na = DIN * HDIM, n1 = HDIM * HDIM;

  // prep: zero degi | posmap+batch | weight pre-split (one kernel)
  const int prepWork = N + n_tool + n_query + na + 2 * n1;
  k_prep<<<(prepWork + 255) / 256, 256, 0, stream>>>(
      degi, N, tool_idx, query_idx, batch_vec, pos, (float*)d_out, n_tool, n_query,
      W_align, W1, W2, WthA, WtlA, Wth1, Wtl1, Wth2, Wtl2, na, n1);

  // CSR build
  k_count<<<nblkE, 256, 0, stream>>>(edge_dst, degi, E);
  k_scan1<<<nblkN, 256, 0, stream>>>(degi, row_start, bsum, dinv, N);
  k_scan23<<<(N + 511) / 512, 512, 0, stream>>>(row_start, bsum, nblkN, N, E);
  k_fill<<<nblkE, 256, 0, stream>>>(edge_src, edge_dst, row_start, degi, dinv,
                                    csr, E);

  const int gemmBlocks = (N + 255) / 256;   // 256-row tiles, 512 threads
  const int waveBlocks = (N * 64 + 255) / 256;

  // h = x @ W_align + b_align  (A f32, out bf16)
  k_gemm_bf<768, true, false, 2><<<gemmBlocks, 512, 0, stream>>>(
      x, WthA, WtlA, b_align, h, N);

  // layer 1 (A bf16 direct, m out fp16)
  k_gemm_bf<128, false, true, 1><<<gemmBlocks, 512, 0, stream>>>(
      h, Wth1, Wtl1, nullptr, m, N);
  k_gather<false><<<waveBlocks, 256, 0, stream>>>(
      (const __half2*)m, (unsigned*)h, row_start, csr, dinv, b1,
      nullptr, nullptr, nullptr, nullptr, N);
  // layer 2 + fused output projection
  k_gemm_bf<128, false, true, 1><<<gemmBlocks, 512, 0, stream>>>(
      h, Wth2, Wtl2, nullptr, m, N);
  k_gather<true><<<waveBlocks, 256, 0, stream>>>(
      (const __half2*)m, (unsigned*)h, row_start, csr, dinv, b2,
      W_out, b_out, pos, (float*)d_out, N);
}

// Round 21
// 286.774 us; speedup vs baseline: 1.0190x; 1.0190x over previous
//
#include <hip/hip_runtime.h>
#include <hip/hip_fp16.h>

// QueryAwareGNN: N=100000, E=600000, DIN=768, H=128, G=100.
// Output (flat f32): tool_logits[99000] | query_logits[1000] | tool_batch_index[99000]

#define HDIM 128

typedef short s16x8 __attribute__((ext_vector_type(8)));
typedef unsigned short u16;
typedef unsigned short u16x8 __attribute__((ext_vector_type(8)));
typedef float f32x4 __attribute__((ext_vector_type(4)));

// split f32 into hi/lo bf16 (truncation hi; lo captures next 8 mantissa bits)
__device__ inline void split2(float f, u16& hi, u16& lo) {
  unsigned u = __builtin_bit_cast(unsigned, f);
  hi = (u16)(u >> 16);
  float fh = __builtin_bit_cast(float, u & 0xFFFF0000u);
  float fl = f - fh;
  lo = (u16)(__builtin_bit_cast(unsigned, fl) >> 16);
}

// round-to-nearest-even f32 -> bf16
__device__ inline u16 bf16rne(float f) {
  unsigned u = __builtin_bit_cast(unsigned, f);
  u += 0x7FFFu + ((u >> 16) & 1u);
  return (u16)(u >> 16);
}

// convert 8 f32 (two f32x4) -> u16x8 of bf16 (RNE)
__device__ inline u16x8 cvt8(f32x4 a, f32x4 b) {
  u16x8 r;
  r[0] = bf16rne(a[0]); r[1] = bf16rne(a[1]);
  r[2] = bf16rne(a[2]); r[3] = bf16rne(a[3]);
  r[4] = bf16rne(b[0]); r[5] = bf16rne(b[1]);
  r[6] = bf16rne(b[2]); r[7] = bf16rne(b[3]);
  return r;
}

// ---------------- prep: zero degi | posmap+batch | weight pre-split ----------------
// One kernel, three independent index segments.
// Weight tiled layout (R12): th[(k/32)][n][k%32] (each k-block = exact 8KB LDS image)

__global__ __launch_bounds__(256) void k_prep(int* __restrict__ degi, int N,
                                              const int* __restrict__ tool_idx,
                                              const int* __restrict__ query_idx,
                                              const int* __restrict__ batch_vec,
                                              int* __restrict__ pos,
                                              float* __restrict__ out,
                                              int n_tool, int n_query,
                                              const float* __restrict__ Wa,
                                              const float* __restrict__ W1,
                                              const float* __restrict__ W2,
                                              u16* __restrict__ tha, u16* __restrict__ tla,
                                              u16* __restrict__ th1, u16* __restrict__ tl1,
                                              u16* __restrict__ th2, u16* __restrict__ tl2,
                                              int na, int n1) {
  int g = blockIdx.x * 256 + threadIdx.x;
  if (g < N) degi[g] = 0;
  int g1 = g - N;
  if (g1 >= 0 && g1 < n_tool) {
    int nd = tool_idx[g1];
    pos[nd] = g1;
    out[n_tool + n_query + g1] = (float)batch_vec[nd];
  } else if (g1 >= n_tool && g1 < n_tool + n_query) {
    int q = g1 - n_tool;
    pos[query_idx[q]] = n_tool + q;
  }
  int g2 = g - N - n_tool - n_query;
  if (g2 >= 0 && g2 < na + 2 * n1) {
    const float* W;
    u16 *th, *tl;
    int idx;
    if (g2 < na) { W = Wa; th = tha; tl = tla; idx = g2; }
    else if (g2 < na + n1) { W = W1; th = th1; tl = tl1; idx = g2 - na; }
    else { W = W2; th = th2; tl = tl2; idx = g2 - na - n1; }
    int n = idx & 127, k = idx >> 7;
    u16 h, l;
    split2(W[idx], h, l);
    int o = ((k >> 5) << 12) | (n << 5) | (k & 31);
    th[o] = h;
    tl[o] = l;
  }
}

// ---------------- CSR build ----------------

__global__ __launch_bounds__(256) void k_count(const int* __restrict__ dst,
                                               int* __restrict__ degi, int E) {
  int g = blockIdx.x * 256 + threadIdx.x;
  if (g < E) atomicAdd(&degi[dst[g]], 1);
}

// scan1: per-256-block exclusive scan; also dinv (fused)
__global__ __launch_bounds__(256) void k_scan1(const int* __restrict__ in,
                                               int* __restrict__ out,
                                               int* __restrict__ bsum,
                                               float* __restrict__ dinv, int n) {
  __shared__ int s[256];
  int t = threadIdx.x, g = blockIdx.x * 256 + t;
  int v = (g < n) ? in[g] : 0;
  if (g < n) dinv[g] = rsqrtf((float)(v + 1));  // +1 self-loop
  s[t] = v;
  for (int off = 1; off < 256; off <<= 1) {
    __syncthreads();
    int x = (t >= off) ? s[t - off] : 0;
    __syncthreads();
    s[t] += x;
  }
  if (g < n) out[g] = s[t] - v;
  if (t == 255) bsum[blockIdx.x] = s[255];
}

// scan23: every block re-scans bsum (nb<=512) in LDS and applies its offsets.
__global__ __launch_bounds__(512) void k_scan23(int* __restrict__ row_start,
                                                const int* __restrict__ bsum,
                                                int nb, int n, int total) {
  __shared__ int s[512];
  int t = threadIdx.x;
  int v = (t < nb) ? bsum[t] : 0;
  s[t] = v;
  for (int off = 1; off < 512; off <<= 1) {
    __syncthreads();
    int x = (t >= off) ? s[t - off] : 0;
    __syncthreads();
    s[t] += x;
  }
  __syncthreads();           // s[t] = inclusive prefix of bsum
  int g = blockIdx.x * 512 + t;
  int bi = g >> 8;           // which 256-block this element came from
  int off = (bi == 0) ? 0 : s[bi - 1];
  if (g < n) row_start[g] += off;
  if (g == 0) row_start[n] = total;
}

// fill: claims slots by decrementing degi (dead after scan1) -> no fillc buffer.
// csr packed as int2 {src, norm-bits}: one 8B random write per edge.
__global__ __launch_bounds__(256) void k_fill(const int* __restrict__ src,
                                              const int* __restrict__ dst,
                                              const int* __restrict__ row_start,
                                              int* __restrict__ degi,
                                              const float* __restrict__ dinv,
                                              int2* __restrict__ csr, int E) {
  int g = blockIdx.x * 256 + threadIdx.x;
  if (g < E) {
    int s = src[g], d = dst[g];
    int p = atomicSub(&degi[d], 1) - 1;   // deg-1 .. 0, unique per edge
    int o = row_start[d] + p;
    float nr = dinv[s] * dinv[d];
    csr[o] = make_int2(s, __float_as_int(nr));
  }
}

// ---------------- MFMA GEMM: C[M,128] = A[M,K] @ W[K,128] (+bias) ----------------
// 128x128 tile, 256 threads (4 waves 2x2), BK=32 (R18 structure -- measured best).
// A-tile LDS is ALWAYS bf16 u16[128][40] (10.25KB): AHALF=false loads f32 and
// converts (RNE) in registers before staging (bit-identical to cvt-at-fragment);
// AHALF=true stages bf16 directly. Inner loop is conversion-free for both.
// GEMM768 LDS: 30.7KB -> 5 blocks/CU (was 4).
// B split hi+lo bf16, pre-tiled, pad-40 rows, reg-staged.
// OUTT: 1 = fp16 out (m buffer), 2 = bf16 out (h buffer).

template <int K, bool BIAS, bool AHALF, int OUTT>
__global__ __launch_bounds__(256) void k_gemm_bf(const void* __restrict__ Av,
                                                 const u16* __restrict__ Bth,
                                                 const u16* __restrict__ Btl,
                                                 const float* __restrict__ bias,
                                                 void* __restrict__ Cv, int M) {
  __shared__ u16 Ah[128][40];    // bf16 A tile, stride 40 (80B rows)
  __shared__ u16 Bh[128][40];    // B transposed: Bh[n][k], stride 40
  __shared__ u16 Bl[128][40];

  const int t = threadIdx.x;
  const int m0 = blockIdx.x << 7;
  const int lane = t & 63, w = t >> 6;
  const int wm = (w >> 1) << 6, wn = (w & 1) << 6;
  const int fr = lane & 15;          // row (A) / col (B) within fragment
  const int fk = (lane >> 4) << 3;   // k offset within fragment
  const int srow = t >> 1;           // staging: row 0..127
  const int scol = (t & 1) << 4;     // staging: col 0 or 16 (elements)

  f32x4 acc[4][4] = {};
  const bool valid = (m0 + srow) < M;

  // A-staging state
  const float* arowF = nullptr;
  const u16* arowH = nullptr;
  f32x4 v0 = {}, v1 = {}, v2 = {}, v3 = {};
  u16x8 ha0 = {}, ha1 = {};
  if constexpr (AHALF) {
    arowH = (const u16*)Av + (size_t)(m0 + srow) * K + scol;
    if (valid) {
      ha0 = *(const u16x8*)(arowH + 0);
      ha1 = *(const u16x8*)(arowH + 8);
    }
  } else {
    arowF = (const float*)Av + (size_t)(m0 + srow) * K + scol;
    if (valid) {
      v0 = *(const f32x4*)(arowF + 0);
      v1 = *(const f32x4*)(arowF + 4);
      v2 = *(const f32x4*)(arowF + 8);
      v3 = *(const f32x4*)(arowF + 12);
    }
  }

  for (int kb = 0; kb < K; kb += 32) {
    // ---- A stage into LDS (bf16 both paths)
    if constexpr (AHALF) {
      *(u16x8*)&Ah[srow][scol] = ha0;
      *(u16x8*)&Ah[srow][scol + 8] = ha1;
    } else {
      *(u16x8*)&Ah[srow][scol] = cvt8(v0, v1);
      *(u16x8*)&Ah[srow][scol + 8] = cvt8(v2, v3);
    }

    // ---- B stage: coalesced 32B/thread from pre-tiled weights
    {
      const u16* bsrc = Bth + ((size_t)(kb >> 5) << 12) + (t << 4);
      u16x8 p0 = *(const u16x8*)bsrc;
      u16x8 p1 = *(const u16x8*)(bsrc + 8);
      const u16* bsrc2 = Btl + ((size_t)(kb >> 5) << 12) + (t << 4);
      u16x8 q0 = *(const u16x8*)bsrc2;
      u16x8 q1 = *(const u16x8*)(bsrc2 + 8);
      int bn = t >> 1, bseg = (t & 1) << 4;
      *(u16x8*)&Bh[bn][bseg] = p0;
      *(u16x8*)&Bh[bn][bseg + 8] = p1;
      *(u16x8*)&Bl[bn][bseg] = q0;
      *(u16x8*)&Bl[bn][bseg + 8] = q1;
    }
    __syncthreads();

    // ---- prefetch next A tile into regs (latency hides under MFMA)
    if (valid && kb + 32 < K) {
      if constexpr (AHALF) {
        ha0 = *(const u16x8*)(arowH + kb + 32);
        ha1 = *(const u16x8*)(arowH + kb + 40);
      } else {
        const float* ap = arowF + kb + 32;
        v0 = *(const f32x4*)(ap + 0);
        v1 = *(const f32x4*)(ap + 4);
        v2 = *(const f32x4*)(ap + 8);
        v3 = *(const f32x4*)(ap + 12);
      }
    }

    // ---- fragments + 32 MFMAs (conversion-free)
    s16x8 ah[4], bh[4], bl[4];
#pragma unroll
    for (int i = 0; i < 4; ++i) {
      ah[i] = *(const s16x8*)&Ah[wm + (i << 4) + fr][fk];
      bh[i] = *(const s16x8*)&Bh[wn + (i << 4) + fr][fk];
      bl[i] = *(const s16x8*)&Bl[wn + (i << 4) + fr][fk];
    }
#pragma unroll
    for (int i = 0; i < 4; ++i)
#pragma unroll
      for (int j = 0; j < 4; ++j) {
        acc[i][j] = __builtin_amdgcn_mfma_f32_16x16x32_bf16(ah[i], bh[j], acc[i][j], 0, 0, 0);
        acc[i][j] = __builtin_amdgcn_mfma_f32_16x16x32_bf16(ah[i], bl[j], acc[i][j], 0, 0, 0);
      }
    __syncthreads();
  }

  // ---- epilogue: C/D layout col=lane&15, row=(lane>>4)*4+reg
  const int cr = (lane >> 4) << 2;
#pragma unroll
  for (int i = 0; i < 4; ++i) {
    int mbase = m0 + wm + (i << 4) + cr;
#pragma unroll
    for (int j = 0; j < 4; ++j) {
      int n = wn + (j << 4) + fr;
      float bv = BIAS ? bias[n] : 0.0f;
#pragma unroll
      for (int r = 0; r < 4; ++r) {
        if (mbase + r < M) {
          float val = acc[i][j][r] + bv;
          if constexpr (OUTT == 1) {
            ((__half*)Cv)[(size_t)(mbase + r) * HDIM + n] = __float2half_rn(val);
          } else {
            ((u16*)Cv)[(size_t)(mbase + r) * HDIM + n] = bf16rne(val);
          }
        }
      }
    }
  }
}

// ---------------- gather + bias + relu + residual ----------------
// One wave per node; m fp16 (256B/row gathers), h bf16 (packed 2/lane).
// Edge (src,norm) packed int2, loaded 64-at-a-time and broadcast via shfl.
// 4-way unrolled edge loop with quad accumulator pairs.
// FINAL=true: fuse output projection and skip the h write.

template <bool FINAL>
__global__ __launch_bounds__(256) void k_gather(const __half2* __restrict__ m2,
                                                unsigned* __restrict__ h,
                                                const int* __restrict__ row_start,
                                                const int2* __restrict__ csr,
                                                const float* __restrict__ dinv,
                                                const float* __restrict__ bias,
                                                const float* __restrict__ Wout,
                                                const float* __restrict__ bout,
                                                const int* __restrict__ pos,
                                                float* __restrict__ out, int N) {
  int wid = (blockIdx.x * 256 + threadIdx.x) >> 6;
  int lane = threadIdx.x & 63;
  if (wid >= N) return;
  float di = dinv[wid];
  float sl = di * di;
  float2 mv = __half22float2(m2[(size_t)wid * 64 + lane]);
  float ax = mv.x * sl, ay = mv.y * sl;   // accumulator pair 0 (+self-loop)
  float bx = 0.f, by = 0.f;               // pair 1
  float cx = 0.f, cy = 0.f;               // pair 2
  float dx = 0.f, dy = 0.f;               // pair 3
  int e0 = row_start[wid], e1 = row_start[wid + 1];
  for (int base = e0; base < e1; base += 64) {
    int cnt = e1 - base;
    if (cnt > 64) cnt = 64;
    int sL = 0;
    float nL = 0.f;
    if (base + lane < e1) {
      int2 cv = csr[base + lane];
      sL = cv.x;
      nL = __int_as_float(cv.y);
    }
    int j = 0;
    for (; j + 3 < cnt; j += 4) {
      int s0 = __shfl(sL, j);
      int s1 = __shfl(sL, j + 1);
      int s2 = __shfl(sL, j + 2);
      int s3 = __shfl(sL, j + 3);
      float n0 = __shfl(nL, j);
      float n1 = __shfl(nL, j + 1);
      float n2 = __shfl(nL, j + 2);
      float n3 = __shfl(nL, j + 3);
      float2 u0 = __half22float2(m2[(size_t)s0 * 64 + lane]);
      float2 u1 = __half22float2(m2[(size_t)s1 * 64 + lane]);
      float2 u2 = __half22float2(m2[(size_t)s2 * 64 + lane]);
      float2 u3 = __half22float2(m2[(size_t)s3 * 64 + lane]);
      ax = fmaf(u0.x, n0, ax); ay = fmaf(u0.y, n0, ay);
      bx = fmaf(u1.x, n1, bx); by = fmaf(u1.y, n1, by);
      cx = fmaf(u2.x, n2, cx); cy = fmaf(u2.y, n2, cy);
      dx = fmaf(u3.x, n3, dx); dy = fmaf(u3.y, n3, dy);
    }
    for (; j + 1 < cnt; j += 2) {
      int s0 = __shfl(sL, j);
      int s1 = __shfl(sL, j + 1);
      float n0 = __shfl(nL, j);
      float n1 = __shfl(nL, j + 1);
      float2 u0 = __half22float2(m2[(size_t)s0 * 64 + lane]);
      float2 u1 = __half22float2(m2[(size_t)s1 * 64 + lane]);
      ax = fmaf(u0.x, n0, ax); ay = fmaf(u0.y, n0, ay);
      bx = fmaf(u1.x, n1, bx); by = fmaf(u1.y, n1, by);
    }
    if (j < cnt) {
      int s0 = __shfl(sL, j);
      float n0 = __shfl(nL, j);
      float2 u0 = __half22float2(m2[(size_t)s0 * 64 + lane]);
      ax = fmaf(u0.x, n0, ax); ay = fmaf(u0.y, n0, ay);
    }
  }
  ax += bx; cx += dx; ax += cx;
  ay += by; cy += dy; ay += cy;
  float2 bb = ((const float2*)bias)[lane];
  unsigned hw = h[(size_t)wid * 64 + lane];            // 2 bf16 packed
  float hvx = __builtin_bit_cast(float, (hw & 0xFFFFu) << 16);
  float hvy = __builtin_bit_cast(float, hw & 0xFFFF0000u);
  float rx = fmaxf(ax + bb.x, 0.f) + hvx;
  float ry = fmaxf(ay + bb.y, 0.f) + hvy;
  if (FINAL) {
    float2 wv = ((const float2*)Wout)[lane];
    float s = rx * wv.x + ry * wv.y;
#pragma unroll
    for (int off = 32; off > 0; off >>= 1) s += __shfl_down(s, off);
    if (lane == 0) out[pos[wid]] = s + bout[0];
  } else {
    unsigned wout = (unsigned)bf16rne(rx) | ((unsigned)bf16rne(ry) << 16);
    h[(size_t)wid * 64 + lane] = wout;
  }
}

// ---------------- launcher ----------------

extern "C" void kernel_launch(void* const* d_in, const int* in_sizes, int n_in,
                              void* d_out, int out_size, void* d_ws, size_t ws_size,
                              hipStream_t stream) {
  const float* x        = (const float*)d_in[0];
  const int*   edge_src = (const int*)d_in[1];
  const int*   edge_dst = (const int*)d_in[2];
  const int*   batch_vec= (const int*)d_in[3];
  const int*   tool_idx = (const int*)d_in[4];
  const int*   query_idx= (const int*)d_in[5];
  const float* W_align  = (const float*)d_in[6];
  const float* b_align  = (const float*)d_in[7];
  const float* W1       = (const float*)d_in[8];
  const float* b1       = (const float*)d_in[9];
  const float* W2       = (const float*)d_in[10];
  const float* b2       = (const float*)d_in[11];
  const float* W_out    = (const float*)d_in[12];
  const float* b_out    = (const float*)d_in[13];

  const int N   = in_sizes[3];
  const int E   = in_sizes[1];
  const int DIN = in_sizes[0] / N;     // 768
  const int n_tool  = in_sizes[4];
  const int n_query = in_sizes[5];
  (void)n_in; (void)out_size; (void)ws_size;

  char* p = (char*)d_ws;
  auto alloc = [&](size_t bytes) {
    void* r = (void*)p;
    p += (bytes + 255) & ~(size_t)255;
    return r;
  };
  int*   degi      = (int*)alloc((size_t)N * 4);
  float* dinv      = (float*)alloc((size_t)N * 4);
  int*   row_start = (int*)alloc((size_t)(N + 1) * 4);
  int*   pos       = (int*)alloc((size_t)N * 4);
  int2*  csr       = (int2*)alloc((size_t)E * 8);
  u16*   h         = (u16*)alloc((size_t)N * HDIM * 2);   // bf16 activations
  __half* m        = (__half*)alloc((size_t)N * HDIM * 2);
  int*   bsum      = (int*)alloc((size_t)1024 * 4);
  u16*   WthA      = (u16*)alloc((size_t)DIN * HDIM * 2);
  u16*   WtlA      = (u16*)alloc((size_t)DIN * HDIM * 2);
  u16*   Wth1      = (u16*)alloc((size_t)HDIM * HDIM * 2);
  u16*   Wtl1      = (u16*)alloc((size_t)HDIM * HDIM * 2);
  u16*   Wth2      = (u16*)alloc((size_t)HDIM * HDIM * 2);
  u16*   Wtl2      = (u16*)alloc((size_t)HDIM * HDIM * 2);

  const int nblkE = (E + 255) / 256;
  const int nblkN = (N + 255) / 256;   // 391 (<=512 required for scan23)
  const int na = DIN * HDIM, n1 = HDIM * HDIM;

  // prep: zero degi | posmap+batch | weight pre-split (one kernel)
  const int prepWork = N + n_tool + n_query + na + 2 * n1;
  k_prep<<<(prepWork + 255) / 256, 256, 0, stream>>>(
      degi, N, tool_idx, query_idx, batch_vec, pos, (float*)d_out, n_tool, n_query,
      W_align, W1, W2, WthA, WtlA, Wth1, Wtl1, Wth2, Wtl2, na, n1);

  // CSR build
  k_count<<<nblkE, 256, 0, stream>>>(edge_dst, degi, E);
  k_scan1<<<nblkN, 256, 0, stream>>>(degi, row_start, bsum, dinv, N);
  k_scan23<<<(N + 511) / 512, 512, 0, stream>>>(row_start, bsum, nblkN, N, E);
  k_fill<<<nblkE, 256, 0, stream>>>(edge_src, edge_dst, row_start, degi, dinv,
                                    csr, E);

  const int gemmBlocks = (N + 127) / 128;
  const int waveBlocks = (N * 64 + 255) / 256;

  // h = x @ W_align + b_align  (A f32 -> bf16 in regs, out bf16)
  k_gemm_bf<768, true, false, 2><<<gemmBlocks, 256, 0, stream>>>(
      x, WthA, WtlA, b_align, h, N);

  // layer 1 (A bf16 direct, m out fp16)
  k_gemm_bf<128, false, true, 1><<<gemmBlocks, 256, 0, stream>>>(
      h, Wth1, Wtl1, nullptr, m, N);
  k_gather<false><<<waveBlocks, 256, 0, stream>>>(
      (const __half2*)m, (unsigned*)h, row_start, csr, dinv, b1,
      nullptr, nullptr, nullptr, nullptr, N);
  // layer 2 + fused output projection
  k_gemm_bf<128, false, true, 1><<<gemmBlocks, 256, 0, stream>>>(
      h, Wth2, Wtl2, nullptr, m, N);
  k_gather<true><<<waveBlocks, 256, 0, stream>>>(
      (const __half2*)m, (unsigned*)h, row_start, csr, dinv, b2,
      W_out, b_out, pos, (float*)d_out, N);
}

// Round 22
// 284.066 us; speedup vs baseline: 1.0287x; 1.0095x over previous
//
#include <hip/hip_runtime.h>
#include <hip/hip_fp16.h>

// QueryAwareGNN: N=100000, E=600000, DIN=768, H=128, G=100.
// Output (flat f32): tool_logits[99000] | query_logits[1000] | tool_batch_index[99000]

#define HDIM 128

typedef short s16x8 __attribute__((ext_vector_type(8)));
typedef unsigned short u16;
typedef unsigned short u16x8 __attribute__((ext_vector_type(8)));
typedef float f32x4 __attribute__((ext_vector_type(4)));

// split f32 into hi/lo bf16 (truncation hi; lo captures next 8 mantissa bits)
__device__ inline void split2(float f, u16& hi, u16& lo) {
  unsigned u = __builtin_bit_cast(unsigned, f);
  hi = (u16)(u >> 16);
  float fh = __builtin_bit_cast(float, u & 0xFFFF0000u);
  float fl = f - fh;
  lo = (u16)(__builtin_bit_cast(unsigned, fl) >> 16);
}

// round-to-nearest-even f32 -> bf16
__device__ inline u16 bf16rne(float f) {
  unsigned u = __builtin_bit_cast(unsigned, f);
  u += 0x7FFFu + ((u >> 16) & 1u);
  return (u16)(u >> 16);
}

// convert 8 f32 (two f32x4) -> u16x8 of bf16 (RNE)
__device__ inline u16x8 cvt8(f32x4 a, f32x4 b) {
  u16x8 r;
  r[0] = bf16rne(a[0]); r[1] = bf16rne(a[1]);
  r[2] = bf16rne(a[2]); r[3] = bf16rne(a[3]);
  r[4] = bf16rne(b[0]); r[5] = bf16rne(b[1]);
  r[6] = bf16rne(b[2]); r[7] = bf16rne(b[3]);
  return r;
}

// ---------------- prep: zero degi | posmap+batch | weight pre-split ----------------
// One kernel, three independent index segments.
// Weight tiled layout (R12): th[(k/32)][n][k%32] (each k-block = exact 8KB LDS image)

__global__ __launch_bounds__(256) void k_prep(int* __restrict__ degi, int N,
                                              const int* __restrict__ tool_idx,
                                              const int* __restrict__ query_idx,
                                              const int* __restrict__ batch_vec,
                                              int* __restrict__ pos,
                                              float* __restrict__ out,
                                              int n_tool, int n_query,
                                              const float* __restrict__ Wa,
                                              const float* __restrict__ W1,
                                              const float* __restrict__ W2,
                                              u16* __restrict__ tha, u16* __restrict__ tla,
                                              u16* __restrict__ th1, u16* __restrict__ tl1,
                                              u16* __restrict__ th2, u16* __restrict__ tl2,
                                              int na, int n1) {
  int g = blockIdx.x * 256 + threadIdx.x;
  if (g < N) degi[g] = 0;
  int g1 = g - N;
  if (g1 >= 0 && g1 < n_tool) {
    int nd = tool_idx[g1];
    pos[nd] = g1;
    out[n_tool + n_query + g1] = (float)batch_vec[nd];
  } else if (g1 >= n_tool && g1 < n_tool + n_query) {
    int q = g1 - n_tool;
    pos[query_idx[q]] = n_tool + q;
  }
  int g2 = g - N - n_tool - n_query;
  if (g2 >= 0 && g2 < na + 2 * n1) {
    const float* W;
    u16 *th, *tl;
    int idx;
    if (g2 < na) { W = Wa; th = tha; tl = tla; idx = g2; }
    else if (g2 < na + n1) { W = W1; th = th1; tl = tl1; idx = g2 - na; }
    else { W = W2; th = th2; tl = tl2; idx = g2 - na - n1; }
    int n = idx & 127, k = idx >> 7;
    u16 h, l;
    split2(W[idx], h, l);
    int o = ((k >> 5) << 12) | (n << 5) | (k & 31);
    th[o] = h;
    tl[o] = l;
  }
}

// ---------------- CSR build ----------------

__global__ __launch_bounds__(256) void k_count(const int* __restrict__ dst,
                                               int* __restrict__ degi, int E) {
  int g = blockIdx.x * 256 + threadIdx.x;
  if (g < E) atomicAdd(&degi[dst[g]], 1);
}

// scan1: per-256-block exclusive scan; also dinv (fused)
__global__ __launch_bounds__(256) void k_scan1(const int* __restrict__ in,
                                               int* __restrict__ out,
                                               int* __restrict__ bsum,
                                               float* __restrict__ dinv, int n) {
  __shared__ int s[256];
  int t = threadIdx.x, g = blockIdx.x * 256 + t;
  int v = (g < n) ? in[g] : 0;
  if (g < n) dinv[g] = rsqrtf((float)(v + 1));  // +1 self-loop
  s[t] = v;
  for (int off = 1; off < 256; off <<= 1) {
    __syncthreads();
    int x = (t >= off) ? s[t - off] : 0;
    __syncthreads();
    s[t] += x;
  }
  if (g < n) out[g] = s[t] - v;
  if (t == 255) bsum[blockIdx.x] = s[255];
}

// scan23: every block re-scans bsum (nb<=512) in LDS and applies its offsets.
__global__ __launch_bounds__(512) void k_scan23(int* __restrict__ row_start,
                                                const int* __restrict__ bsum,
                                                int nb, int n, int total) {
  __shared__ int s[512];
  int t = threadIdx.x;
  int v = (t < nb) ? bsum[t] : 0;
  s[t] = v;
  for (int off = 1; off < 512; off <<= 1) {
    __syncthreads();
    int x = (t >= off) ? s[t - off] : 0;
    __syncthreads();
    s[t] += x;
  }
  __syncthreads();           // s[t] = inclusive prefix of bsum
  int g = blockIdx.x * 512 + t;
  int bi = g >> 8;           // which 256-block this element came from
  int off = (bi == 0) ? 0 : s[bi - 1];
  if (g < n) row_start[g] += off;
  if (g == 0) row_start[n] = total;
}

// fill: claims slots by decrementing degi (dead after scan1) -> no fillc buffer.
// csr packed as int2 {src, norm-bits}: one 8B random write per edge.
__global__ __launch_bounds__(256) void k_fill(const int* __restrict__ src,
                                              const int* __restrict__ dst,
                                              const int* __restrict__ row_start,
                                              int* __restrict__ degi,
                                              const float* __restrict__ dinv,
                                              int2* __restrict__ csr, int E) {
  int g = blockIdx.x * 256 + threadIdx.x;
  if (g < E) {
    int s = src[g], d = dst[g];
    int p = atomicSub(&degi[d], 1) - 1;   // deg-1 .. 0, unique per edge
    int o = row_start[d] + p;
    float nr = dinv[s] * dinv[d];
    csr[o] = make_int2(s, __float_as_int(nr));
  }
}

// ---------------- MFMA GEMM: C[M,128] = A[M,K] @ W[K,128] (+bias) ----------------
// 128x128 tile, 256 threads (4 waves 2x2), BK=32 (R18 structure -- measured best).
// A-tile LDS is ALWAYS bf16 u16[128][40]: AHALF=false loads f32 and converts (RNE)
// in registers before staging; AHALF=true stages bf16 directly. Inner loop is
// conversion-free for both. B split hi+lo bf16, pre-tiled, pad-40 rows, reg-staged.
// OUTT: 1 = fp16 out (m buffer), 2 = bf16 out (h buffer).

template <int K, bool BIAS, bool AHALF, int OUTT>
__global__ __launch_bounds__(256) void k_gemm_bf(const void* __restrict__ Av,
                                                 const u16* __restrict__ Bth,
                                                 const u16* __restrict__ Btl,
                                                 const float* __restrict__ bias,
                                                 void* __restrict__ Cv, int M) {
  __shared__ u16 Ah[128][40];    // bf16 A tile, stride 40 (80B rows)
  __shared__ u16 Bh[128][40];    // B transposed: Bh[n][k], stride 40
  __shared__ u16 Bl[128][40];

  const int t = threadIdx.x;
  const int m0 = blockIdx.x << 7;
  const int lane = t & 63, w = t >> 6;
  const int wm = (w >> 1) << 6, wn = (w & 1) << 6;
  const int fr = lane & 15;          // row (A) / col (B) within fragment
  const int fk = (lane >> 4) << 3;   // k offset within fragment
  const int srow = t >> 1;           // staging: row 0..127
  const int scol = (t & 1) << 4;     // staging: col 0 or 16 (elements)

  f32x4 acc[4][4] = {};
  const bool valid = (m0 + srow) < M;

  // A-staging state
  const float* arowF = nullptr;
  const u16* arowH = nullptr;
  f32x4 v0 = {}, v1 = {}, v2 = {}, v3 = {};
  u16x8 ha0 = {}, ha1 = {};
  if constexpr (AHALF) {
    arowH = (const u16*)Av + (size_t)(m0 + srow) * K + scol;
    if (valid) {
      ha0 = *(const u16x8*)(arowH + 0);
      ha1 = *(const u16x8*)(arowH + 8);
    }
  } else {
    arowF = (const float*)Av + (size_t)(m0 + srow) * K + scol;
    if (valid) {
      v0 = *(const f32x4*)(arowF + 0);
      v1 = *(const f32x4*)(arowF + 4);
      v2 = *(const f32x4*)(arowF + 8);
      v3 = *(const f32x4*)(arowF + 12);
    }
  }

  for (int kb = 0; kb < K; kb += 32) {
    // ---- A stage into LDS (bf16 both paths)
    if constexpr (AHALF) {
      *(u16x8*)&Ah[srow][scol] = ha0;
      *(u16x8*)&Ah[srow][scol + 8] = ha1;
    } else {
      *(u16x8*)&Ah[srow][scol] = cvt8(v0, v1);
      *(u16x8*)&Ah[srow][scol + 8] = cvt8(v2, v3);
    }

    // ---- B stage: coalesced 32B/thread from pre-tiled weights
    {
      const u16* bsrc = Bth + ((size_t)(kb >> 5) << 12) + (t << 4);
      u16x8 p0 = *(const u16x8*)bsrc;
      u16x8 p1 = *(const u16x8*)(bsrc + 8);
      const u16* bsrc2 = Btl + ((size_t)(kb >> 5) << 12) + (t << 4);
      u16x8 q0 = *(const u16x8*)bsrc2;
      u16x8 q1 = *(const u16x8*)(bsrc2 + 8);
      int bn = t >> 1, bseg = (t & 1) << 4;
      *(u16x8*)&Bh[bn][bseg] = p0;
      *(u16x8*)&Bh[bn][bseg + 8] = p1;
      *(u16x8*)&Bl[bn][bseg] = q0;
      *(u16x8*)&Bl[bn][bseg + 8] = q1;
    }
    __syncthreads();

    // ---- prefetch next A tile into regs (latency hides under MFMA)
    if (valid && kb + 32 < K) {
      if constexpr (AHALF) {
        ha0 = *(const u16x8*)(arowH + kb + 32);
        ha1 = *(const u16x8*)(arowH + kb + 40);
      } else {
        const float* ap = arowF + kb + 32;
        v0 = *(const f32x4*)(ap + 0);
        v1 = *(const f32x4*)(ap + 4);
        v2 = *(const f32x4*)(ap + 8);
        v3 = *(const f32x4*)(ap + 12);
      }
    }

    // ---- fragments + 32 MFMAs (conversion-free)
    s16x8 ah[4], bh[4], bl[4];
#pragma unroll
    for (int i = 0; i < 4; ++i) {
      ah[i] = *(const s16x8*)&Ah[wm + (i << 4) + fr][fk];
      bh[i] = *(const s16x8*)&Bh[wn + (i << 4) + fr][fk];
      bl[i] = *(const s16x8*)&Bl[wn + (i << 4) + fr][fk];
    }
#pragma unroll
    for (int i = 0; i < 4; ++i)
#pragma unroll
      for (int j = 0; j < 4; ++j) {
        acc[i][j] = __builtin_amdgcn_mfma_f32_16x16x32_bf16(ah[i], bh[j], acc[i][j], 0, 0, 0);
        acc[i][j] = __builtin_amdgcn_mfma_f32_16x16x32_bf16(ah[i], bl[j], acc[i][j], 0, 0, 0);
      }
    __syncthreads();
  }

  // ---- epilogue: C/D layout col=lane&15, row=(lane>>4)*4+reg
  const int cr = (lane >> 4) << 2;
#pragma unroll
  for (int i = 0; i < 4; ++i) {
    int mbase = m0 + wm + (i << 4) + cr;
#pragma unroll
    for (int j = 0; j < 4; ++j) {
      int n = wn + (j << 4) + fr;
      float bv = BIAS ? bias[n] : 0.0f;
#pragma unroll
      for (int r = 0; r < 4; ++r) {
        if (mbase + r < M) {
          float val = acc[i][j][r] + bv;
          if constexpr (OUTT == 1) {
            ((__half*)Cv)[(size_t)(mbase + r) * HDIM + n] = __float2half_rn(val);
          } else {
            ((u16*)Cv)[(size_t)(mbase + r) * HDIM + n] = bf16rne(val);
          }
        }
      }
    }
  }
}

// ---------------- gather + bias + relu + residual ----------------
// One wave per node; m fp16 (256B/row gathers), h bf16 (packed 2/lane).
// Edge (src,norm) packed int2, loaded 64-at-a-time and broadcast via shfl.
// 8-way unrolled edge loop with 8 accumulator pairs (8 outstanding gathers),
// falling through 4-way / 2-way / 1 tails. FINAL=true: fuse output projection.

template <bool FINAL>
__global__ __launch_bounds__(256) void k_gather(const __half2* __restrict__ m2,
                                                unsigned* __restrict__ h,
                                                const int* __restrict__ row_start,
                                                const int2* __restrict__ csr,
                                                const float* __restrict__ dinv,
                                                const float* __restrict__ bias,
                                                const float* __restrict__ Wout,
                                                const float* __restrict__ bout,
                                                const int* __restrict__ pos,
                                                float* __restrict__ out, int N) {
  int wid = (blockIdx.x * 256 + threadIdx.x) >> 6;
  int lane = threadIdx.x & 63;
  if (wid >= N) return;
  float di = dinv[wid];
  float sl = di * di;
  float2 mv = __half22float2(m2[(size_t)wid * 64 + lane]);
  float accx[8], accy[8];
#pragma unroll
  for (int q = 0; q < 8; ++q) { accx[q] = 0.f; accy[q] = 0.f; }
  accx[0] = mv.x * sl; accy[0] = mv.y * sl;   // self-loop into pair 0
  int e0 = row_start[wid], e1 = row_start[wid + 1];
  for (int base = e0; base < e1; base += 64) {
    int cnt = e1 - base;
    if (cnt > 64) cnt = 64;
    int sL = 0;
    float nL = 0.f;
    if (base + lane < e1) {
      int2 cv = csr[base + lane];
      sL = cv.x;
      nL = __int_as_float(cv.y);
    }
    int j = 0;
    for (; j + 7 < cnt; j += 8) {
#pragma unroll
      for (int q = 0; q < 8; ++q) {
        int sq = __shfl(sL, j + q);
        float nq = __shfl(nL, j + q);
        float2 uq = __half22float2(m2[(size_t)sq * 64 + lane]);
        accx[q] = fmaf(uq.x, nq, accx[q]);
        accy[q] = fmaf(uq.y, nq, accy[q]);
      }
    }
    for (; j + 3 < cnt; j += 4) {
#pragma unroll
      for (int q = 0; q < 4; ++q) {
        int sq = __shfl(sL, j + q);
        float nq = __shfl(nL, j + q);
        float2 uq = __half22float2(m2[(size_t)sq * 64 + lane]);
        accx[q] = fmaf(uq.x, nq, accx[q]);
        accy[q] = fmaf(uq.y, nq, accy[q]);
      }
    }
    for (; j + 1 < cnt; j += 2) {
#pragma unroll
      for (int q = 0; q < 2; ++q) {
        int sq = __shfl(sL, j + q);
        float nq = __shfl(nL, j + q);
        float2 uq = __half22float2(m2[(size_t)sq * 64 + lane]);
        accx[q] = fmaf(uq.x, nq, accx[q]);
        accy[q] = fmaf(uq.y, nq, accy[q]);
      }
    }
    if (j < cnt) {
      int sq = __shfl(sL, j);
      float nq = __shfl(nL, j);
      float2 uq = __half22float2(m2[(size_t)sq * 64 + lane]);
      accx[0] = fmaf(uq.x, nq, accx[0]);
      accy[0] = fmaf(uq.y, nq, accy[0]);
    }
  }
  // tree-reduce 8 pairs
  float ax = ((accx[0] + accx[1]) + (accx[2] + accx[3])) +
             ((accx[4] + accx[5]) + (accx[6] + accx[7]));
  float ay = ((accy[0] + accy[1]) + (accy[2] + accy[3])) +
             ((accy[4] + accy[5]) + (accy[6] + accy[7]));
  float2 bb = ((const float2*)bias)[lane];
  unsigned hw = h[(size_t)wid * 64 + lane];            // 2 bf16 packed
  float hvx = __builtin_bit_cast(float, (hw & 0xFFFFu) << 16);
  float hvy = __builtin_bit_cast(float, hw & 0xFFFF0000u);
  float rx = fmaxf(ax + bb.x, 0.f) + hvx;
  float ry = fmaxf(ay + bb.y, 0.f) + hvy;
  if (FINAL) {
    float2 wv = ((const float2*)Wout)[lane];
    float s = rx * wv.x + ry * wv.y;
#pragma unroll
    for (int off = 32; off > 0; off >>= 1) s += __shfl_down(s, off);
    if (lane == 0) out[pos[wid]] = s + bout[0];
  } else {
    unsigned wout = (unsigned)bf16rne(rx) | ((unsigned)bf16rne(ry) << 16);
    h[(size_t)wid * 64 + lane] = wout;
  }
}

// ---------------- launcher ----------------

extern "C" void kernel_launch(void* const* d_in, const int* in_sizes, int n_in,
                              void* d_out, int out_size, void* d_ws, size_t ws_size,
                              hipStream_t stream) {
  const float* x        = (const float*)d_in[0];
  const int*   edge_src = (const int*)d_in[1];
  const int*   edge_dst = (const int*)d_in[2];
  const int*   batch_vec= (const int*)d_in[3];
  const int*   tool_idx = (const int*)d_in[4];
  const int*   query_idx= (const int*)d_in[5];
  const float* W_align  = (const float*)d_in[6];
  const float* b_align  = (const float*)d_in[7];
  const float* W1       = (const float*)d_in[8];
  const float* b1       = (const float*)d_in[9];
  const float* W2       = (const float*)d_in[10];
  const float* b2       = (const float*)d_in[11];
  const float* W_out    = (const float*)d_in[12];
  const float* b_out    = (const float*)d_in[13];

  const int N   = in_sizes[3];
  const int E   = in_sizes[1];
  const int DIN = in_sizes[0] / N;     // 768
  const int n_tool  = in_sizes[4];
  const int n_query = in_sizes[5];
  (void)n_in; (void)out_size; (void)ws_size;

  char* p = (char*)d_ws;
  auto alloc = [&](size_t bytes) {
    void* r = (void*)p;
    p += (bytes + 255) & ~(size_t)255;
    return r;
  };
  int*   degi      = (int*)alloc((size_t)N * 4);
  float* dinv      = (float*)alloc((size_t)N * 4);
  int*   row_start = (int*)alloc((size_t)(N + 1) * 4);
  int*   pos       = (int*)alloc((size_t)N * 4);
  int2*  csr       = (int2*)alloc((size_t)E * 8);
  u16*   h         = (u16*)alloc((size_t)N * HDIM * 2);   // bf16 activations
  __half* m        = (__half*)alloc((size_t)N * HDIM * 2);
  int*   bsum      = (int*)alloc((size_t)1024 * 4);
  u16*   WthA      = (u16*)alloc((size_t)DIN * HDIM * 2);
  u16*   WtlA      = (u16*)alloc((size_t)DIN * HDIM * 2);
  u16*   Wth1      = (u16*)alloc((size_t)HDIM * HDIM * 2);
  u16*   Wtl1      = (u16*)alloc((size_t)HDIM * HDIM * 2);
  u16*   Wth2      = (u16*)alloc((size_t)HDIM * HDIM * 2);
  u16*   Wtl2      = (u16*)alloc((size_t)HDIM * HDIM * 2);

  const int nblkE = (E + 255) / 256;
  const int nblkN = (N + 255) / 256;   // 391 (<=512 required for scan23)
  const int na = DIN * HDIM, n1 = HDIM * HDIM;

  // prep: zero degi | posmap+batch | weight pre-split (one kernel)
  const int prepWork = N + n_tool + n_query + na + 2 * n1;
  k_prep<<<(prepWork + 255) / 256, 256, 0, stream>>>(
      degi, N, tool_idx, query_idx, batch_vec, pos, (float*)d_out, n_tool, n_query,
      W_align, W1, W2, WthA, WtlA, Wth1, Wtl1, Wth2, Wtl2, na, n1);

  // CSR build
  k_count<<<nblkE, 256, 0, stream>>>(edge_dst, degi, E);
  k_scan1<<<nblkN, 256, 0, stream>>>(degi, row_start, bsum, dinv, N);
  k_scan23<<<(N + 511) / 512, 512, 0, stream>>>(row_start, bsum, nblkN, N, E);
  k_fill<<<nblkE, 256, 0, stream>>>(edge_src, edge_dst, row_start, degi, dinv,
                                    csr, E);

  const int gemmBlocks = (N + 127) / 128;
  const int waveBlocks = (N * 64 + 255) / 256;

  // h = x @ W_align + b_align  (A f32 -> bf16 in regs, out bf16)
  k_gemm_bf<768, true, false, 2><<<gemmBlocks, 256, 0, stream>>>(
      x, WthA, WtlA, b_align, h, N);

  // layer 1 (A bf16 direct, m out fp16)
  k_gemm_bf<128, false, true, 1><<<gemmBlocks, 256, 0, stream>>>(
      h, Wth1, Wtl1, nullptr, m, N);
  k_gather<false><<<waveBlocks, 256, 0, stream>>>(
      (const __half2*)m, (unsigned*)h, row_start, csr, dinv, b1,
      nullptr, nullptr, nullptr, nullptr, N);
  // layer 2 + fused output projection
  k_gemm_bf<128, false, true, 1><<<gemmBlocks, 256, 0, stream>>>(
      h, Wth2, Wtl2, nullptr, m, N);
  k_gather<true><<<waveBlocks, 256, 0, stream>>>(
      (const __half2*)m, (unsigned*)h, row_start, csr, dinv, b2,
      W_out, b_out, pos, (float*)d_out, N);
}